// Round 9
// baseline (151.476 us; speedup 1.0000x reference)
//
#include <hip/hip_runtime.h>

// VQ-VAE forward: out = code_out[argmax_c(logits_c(x))], hard_idx = argmax.
// logits are piecewise-linear in scalar x (128 relu breakpoints). Build the
// per-interval UPPER ENVELOPE of the 512 affine logit lines (fp64-exact,
// branchless pairwise L/U-bound formulation); samples classify their interval
// (7 LDS steps) + short binary search in that interval's segment table.
// R6/R7 lesson: in-kernel grid barriers cost 50-80us EACH on gfx950; launch
// boundaries (~3us) are the cheap barrier. R9: 3 launches -- AB tables
// computed redundantly in-LDS inside each env block (bit-identical fma order
// preserves exactness), env_cnt via ballot-free popcount in env2 (no atomics,
// no zero-init), map 4 samples/thread.

#define B_SAMPLES 262144
#define HIDDEN    128
#define NUM_CODES 512
#define EMBED_DIM 256
#define NUM_INT   129     // HIDDEN + 1 intervals
#define MAXSEG    (NUM_INT * NUM_CODES)
#define NENVBLK   (NUM_INT * 8)   // 1032 envelope blocks

// ---- workspace layout (byte offsets) ----
// 0       : t_sorted[128] double
// 2048    : code_out[512] double
// 8192    : env_cnt[129] int
// 36864   : surv[MAXSEG] uchar
// 106496  : Lx[MAXSEG] double
// 638976  : Aglob[MAXSEG] double   (slopes only; reuses old AB region)
// 1703936 : env_xs[MAXSEG] double
// 2236416 : env_idx[MAXSEG] int    -> total ~2.5 MB

__device__ __forceinline__ int classify(const double* ts, double xv) {
  int lo = 0, hi = HIDDEN;   // first index with ts[idx] > xv
  while (lo < hi) { int mid = (lo + hi) >> 1; if (ts[mid] > xv) hi = mid; else lo = mid + 1; }
  return lo;
}

// L1: blocks 0..1031 = envelope for (interval i = blk>>3, line group g = blk&7).
// Each block: rank-sort thresholds (LDS), compute interval's FULL AB row in
// LDS (thread -> lines tid, tid+256; same fma order as before = bit-identical),
// then the proven branchless pairwise L/U scan (4-wave k-split + LDS merge).
// Blocks 1032..1033 = code_out.
__global__ void __launch_bounds__(256) k_envA(
    const float* __restrict__ w1, const float* __restrict__ b1,
    const float* __restrict__ w2, const float* __restrict__ b2,
    const float* __restrict__ emb, const float* __restrict__ decw,
    const float* __restrict__ decb, double* __restrict__ t_sorted,
    double* __restrict__ code_out, double* __restrict__ Aglob,
    unsigned char* __restrict__ surv, double* __restrict__ Lx) {
  const int blk = blockIdx.x, tid = threadIdx.x;
  if (blk >= NENVBLK) {                  // code_out: 2 blocks x 256 codes
    __shared__ double sdw[EMBED_DIM];
    sdw[tid] = (double)decw[tid];
    __syncthreads();
    const int c = (blk - NENVBLK) * 256 + tid;
    const float4* e4 = (const float4*)(emb + c * EMBED_DIM);
    double s = 0.0;
    #pragma unroll 8
    for (int q = 0; q < EMBED_DIM / 4; ++q) {
      const float4 v = e4[q];
      const int j = q * 4;
      s = fma((double)v.x, sdw[j + 0], s);
      s = fma((double)v.y, sdw[j + 1], s);
      s = fma((double)v.z, sdw[j + 2], s);
      s = fma((double)v.w, sdw[j + 3], s);
    }
    code_out[c] = s + (double)decb[0];
    return;
  }
  __shared__ double tloc[HIDDEN], ts[HIDDEN], wj[HIDDEN], bj[HIDDEN];
  __shared__ double2 sAB[NUM_CODES];
  __shared__ double sNL[4][64], sDL[4][64], sNU[4][64], sDU[4][64];
  __shared__ int sDead[4][64];
  const int i = blk >> 3;
  const int g = blk & 7;
  if (tid < HIDDEN) {
    double w = (double)w1[tid], b = (double)b1[tid];
    double t = -b / w;
    if (!isfinite(t)) t = 1e30;
    t = fmin(fmax(t, -1e30), 1e30);
    tloc[tid] = t;
  }
  __syncthreads();
  if (tid < HIDDEN) {                    // stable rank sort, O(128^2)
    double t = tloc[tid];
    int r = 0;
    for (int k = 0; k < HIDDEN; ++k) {
      double tk = tloc[k];
      r += (tk < t) || (tk == t && k < tid);
    }
    ts[r] = t;
  }
  __syncthreads();
  if (blk == 0 && tid < HIDDEN) t_sorted[tid] = ts[tid];
  double xm;
  if (i == 0)           xm = ts[0] - 1.0;
  else if (i == HIDDEN) xm = ts[HIDDEN - 1] + 1.0;
  else                  xm = 0.5 * (ts[i - 1] + ts[i]);
  if (tid < HIDDEN) {
    double w = (double)w1[tid], b = (double)b1[tid];
    bool act = fma(w, xm, b) > 0.0;      // relu sign constant in open interval
    wj[tid] = act ? w : 0.0;
    bj[tid] = act ? b : 0.0;
  }
  __syncthreads();
  #pragma unroll
  for (int half = 0; half < 2; ++half) { // full AB row, 2 lines/thread
    const int c = (half << 8) + tid;
    const float4* r4 = (const float4*)(w2 + c * HIDDEN);
    double A = 0.0, Bv = 0.0;
    #pragma unroll 8
    for (int q = 0; q < HIDDEN / 4; ++q) {
      const float4 v = r4[q];
      const int j = q * 4;
      A  = fma((double)v.x, wj[j + 0], A);
      A  = fma((double)v.y, wj[j + 1], A);
      A  = fma((double)v.z, wj[j + 2], A);
      A  = fma((double)v.w, wj[j + 3], A);
      Bv = fma((double)v.x, bj[j + 0], Bv);
      Bv = fma((double)v.y, bj[j + 1], Bv);
      Bv = fma((double)v.z, bj[j + 2], Bv);
      Bv = fma((double)v.w, bj[j + 3], Bv);
    }
    sAB[c] = make_double2(A, Bv + (double)b2[c]);
  }
  __syncthreads();
  // pairwise scan (proven R2-R8). L as (nL,dL) dL>=0 (dL==0 => -inf);
  // U as (nU,dU) dU<=0 (dU==0 => +inf). Even/odd chain split for latency.
  const int w = tid >> 6, lane = tid & 63;
  const int c = (g << 6) + lane;
  const double2 my = sAB[c];
  double nL0 = -1.0, dL0 = 0.0, nU0 = -1.0, dU0 = 0.0;
  double nL1 = -1.0, dL1 = 0.0, nU1 = -1.0, dU1 = 0.0;
  int dead = 0;
  const int k0 = w << 7;
  #pragma unroll 4
  for (int kk = 0; kk < 128; kk += 2) {
    {
      const int k = k0 + kk;
      const double2 o = sAB[k];          // wave-uniform -> LDS broadcast
      const double d = my.x - o.x;
      const double n = o.y - my.y;       // x* = n/d
      const bool cL = (d > 0.0) && (n * dL0 > nL0 * d);
      const bool cU = (d < 0.0) && (n * dU0 < nU0 * d);
      nL0 = cL ? n : nL0;  dL0 = cL ? d : dL0;
      nU0 = cU ? n : nU0;  dU0 = cU ? d : dU0;
      dead |= (d == 0.0) && ((n > 0.0) || (n == 0.0 && k < c));
    }
    {
      const int k = k0 + kk + 1;
      const double2 o = sAB[k];
      const double d = my.x - o.x;
      const double n = o.y - my.y;
      const bool cL = (d > 0.0) && (n * dL1 > nL1 * d);
      const bool cU = (d < 0.0) && (n * dU1 < nU1 * d);
      nL1 = cL ? n : nL1;  dL1 = cL ? d : dL1;
      nU1 = cU ? n : nU1;  dU1 = cU ? d : dU1;
      dead |= (d == 0.0) && ((n > 0.0) || (n == 0.0 && k < c));
    }
  }
  if (nL1 * dL0 > nL0 * dL1) { nL0 = nL1; dL0 = dL1; }   // valid incl. sentinels
  if (nU1 * dU0 < nU0 * dU1) { nU0 = nU1; dU0 = dU1; }
  sNL[w][lane] = nL0; sDL[w][lane] = dL0;
  sNU[w][lane] = nU0; sDU[w][lane] = dU0;
  sDead[w][lane] = dead;
  __syncthreads();
  if (tid < 64) {                        // wave 0 merges the 4 k-chunks
    double nL = sNL[0][lane], dL = sDL[0][lane];
    double nU = sNU[0][lane], dU = sDU[0][lane];
    int dd = sDead[0][lane];
    #pragma unroll
    for (int wv = 1; wv < 4; ++wv) {
      double cn = sNL[wv][lane], cd = sDL[wv][lane];
      if (cn * dL > nL * cd) { nL = cn; dL = cd; }
      cn = sNU[wv][lane]; cd = sDU[wv][lane];
      if (cn * dU < nU * cd) { nU = cn; dU = cd; }
      dd |= sDead[wv][lane];
    }
    // L < U with dL>=0, dU<=0: multiply by dL*dU (<0) flips: nL*dU > nU*dL
    const int sv = (!dd) && (dL == 0.0 || dU == 0.0 || (nL * dU > nU * dL));
    const int pair = (i << 9) + c;
    surv[pair]  = (unsigned char)sv;
    Lx[pair]    = (dL == 0.0) ? -1e300 : nL / dL;
    Aglob[pair] = my.x;                  // slope for env2's rank
  }
}

// L2: compact survivors into per-interval slope-sorted segment tables, and
// derive env_cnt by counting surv flags (no atomics, no zero-init; both
// half-blocks of an interval write the same count -- benign duplicate).
__global__ void __launch_bounds__(256) k_env2(const double* __restrict__ Aglob,
                       const unsigned char* __restrict__ surv,
                       const double* __restrict__ Lx,
                       double* __restrict__ env_xs, int* __restrict__ env_idx,
                       int* __restrict__ env_cnt) {
  __shared__ double sA[NUM_CODES];
  const int tid = threadIdx.x;
  const int i = blockIdx.x >> 1;
  const int c = ((blockIdx.x & 1) << 8) + tid;
  const int base = i << 9;
  for (int t = tid; t < NUM_CODES; t += 256)
    sA[t] = surv[base + t] ? Aglob[base + t] : 1e300;
  __syncthreads();
  const double myA = sA[c];
  int rank = 0;
  #pragma unroll 8
  for (int k = 0; k < NUM_CODES; ++k) rank += (sA[k] < myA) ? 1 : 0;
  if (surv[base + c]) {
    env_xs[base + rank]  = Lx[base + c];
    env_idx[base + rank] = c;
  }
  if (tid < 64) {                        // wave 0: count survivors
    int cnt = 0;
    #pragma unroll
    for (int m = 0; m < 8; ++m) cnt += (sA[tid + (m << 6)] < 1e300) ? 1 : 0;
    #pragma unroll
    for (int off = 32; off; off >>= 1) cnt += __shfl_xor(cnt, off);
    if (tid == 0) env_cnt[i] = cnt;
  }
}

// L3: per-sample lookup: 7-step LDS classify + ~5-step binary search in the
// interval's segment table (env_xs in L2). 4 samples/thread, float4 I/O --
// four dependent chains interleave for MLP. Unreachable head segments
// (xs <= tlo) are harmless: x > tlo steers the search past them.
__global__ void __launch_bounds__(256) k_map(const float* __restrict__ x,
                       const double* __restrict__ t_sorted,
                       const int* __restrict__ env_cnt,
                       const double* __restrict__ env_xs,
                       const int* __restrict__ env_idx,
                       const double* __restrict__ code_out,
                       float* __restrict__ out, float* __restrict__ idx_out) {
  __shared__ double ts[HIDDEN];
  __shared__ double sco[NUM_CODES];
  __shared__ int scnt[NUM_INT];
  const int tid = threadIdx.x;
  if (tid < HIDDEN) ts[tid] = t_sorted[tid];
  if (tid < NUM_INT) scnt[tid] = env_cnt[tid];
  for (int t = tid; t < NUM_CODES; t += 256) sco[t] = code_out[t];
  __syncthreads();
  const int s = blockIdx.x * 1024 + tid * 4;
  const float4 xv4 = *(const float4*)(x + s);
  const float xs4[4] = {xv4.x, xv4.y, xv4.z, xv4.w};
  float o[4], id[4];
  #pragma unroll
  for (int k = 0; k < 4; ++k) {
    const double xv = (double)xs4[k];
    const int i = classify(ts, xv);
    const int base = i << 9;
    int lo = 0, hi = scnt[i] - 1;
    while (lo < hi) {                    // largest j with xs[j] <= xv
      const int mid = (lo + hi + 1) >> 1;
      if (env_xs[base + mid] <= xv) lo = mid; else hi = mid - 1;
    }
    const int ci = env_idx[base + lo];
    o[k]  = (float)sco[ci];
    id[k] = (float)ci;
  }
  *(float4*)(out + s)     = make_float4(o[0], o[1], o[2], o[3]);
  *(float4*)(idx_out + s) = make_float4(id[0], id[1], id[2], id[3]);
}

extern "C" void kernel_launch(void* const* d_in, const int* in_sizes, int n_in,
                              void* d_out, int out_size, void* d_ws, size_t ws_size,
                              hipStream_t stream) {
  const float* x    = (const float*)d_in[0];
  const float* w1   = (const float*)d_in[1];
  const float* b1   = (const float*)d_in[2];
  const float* w2   = (const float*)d_in[3];
  const float* b2   = (const float*)d_in[4];
  const float* emb  = (const float*)d_in[5];
  const float* decw = (const float*)d_in[6];
  const float* decb = (const float*)d_in[7];

  char* ws = (char*)d_ws;
  double*        t_sorted = (double*)        (ws + 0);
  double*        code_out = (double*)        (ws + 2048);
  int*           env_cnt  = (int*)           (ws + 8192);
  unsigned char* surv     = (unsigned char*) (ws + 36864);
  double*        Lx       = (double*)        (ws + 106496);
  double*        Aglob    = (double*)        (ws + 638976);
  double*        env_xs   = (double*)        (ws + 1703936);
  int*           env_idx  = (int*)           (ws + 2236416);

  float* out  = (float*)d_out;
  float* idxo = out + B_SAMPLES;

  k_envA<<<NENVBLK + 2,      256, 0, stream>>>(w1, b1, w2, b2, emb, decw, decb,
                                               t_sorted, code_out, Aglob, surv, Lx);
  k_env2<<<NUM_INT * 2,      256, 0, stream>>>(Aglob, surv, Lx, env_xs, env_idx, env_cnt);
  k_map <<<B_SAMPLES / 1024, 256, 0, stream>>>(x, t_sorted, env_cnt, env_xs,
                                               env_idx, code_out, out, idxo);
}

// Round 10
// 130.864 us; speedup vs baseline: 1.1575x; 1.1575x over previous
//
#include <hip/hip_runtime.h>

// VQ-VAE forward: out = code_out[argmax_c(logits_c(x))], hard_idx = argmax.
// logits are piecewise-linear in scalar x (128 relu breakpoints). Build the
// per-interval UPPER ENVELOPE of the 512 affine logit lines (fp64-exact,
// branchless pairwise L/U-bound formulation); samples classify their interval
// (bucket table + ~1 refine step) + short binary search in that interval's
// segment table. Lessons: grid barriers cost 50-80us each (R6/R7) -> use
// launch boundaries; don't fuse the AB matvec into env blocks (R9, 8x
// redundant uncoalesced reads). R10 = R8 structure + popcount env_cnt +
// bucket-accelerated classify + 4-sample map.

#define B_SAMPLES 262144
#define HIDDEN    128
#define NUM_CODES 512
#define EMBED_DIM 256
#define NUM_INT   129     // HIDDEN + 1 intervals
#define MAXSEG    (NUM_INT * NUM_CODES)
#define NBUCK     4096

// ---- workspace layout (byte offsets) ----
// 0       : t_sorted[128] double
// 2048    : code_out[512] double
// 8192    : env_cnt[129] int
// 16384   : ibuck[NBUCK+1] uchar    (interval of each bucket's lower edge)
// 36864   : surv[MAXSEG] uchar
// 106496  : Lx[MAXSEG] double
// 638976  : AB[MAXSEG] double2
// 1703936 : env_xs[MAXSEG] double
// 2236416 : env_idx[MAXSEG] int     -> total ~2.5 MB

__device__ __forceinline__ int classify(const double* ts, double xv) {
  int lo = 0, hi = HIDDEN;   // first index with ts[idx] > xv
  while (lo < hi) { int mid = (lo + hi) >> 1; if (ts[mid] > xv) hi = mid; else lo = mid + 1; }
  return lo;
}

// sort thresholds into shared ts[] (stable rank sort, O(128^2), ~1us)
__device__ __forceinline__ void sort_thresholds(const float* w1, const float* b1,
                                                double* tloc, double* ts) {
  const int tid = threadIdx.x;
  if (tid < HIDDEN) {
    double w = (double)w1[tid], b = (double)b1[tid];
    double t = -b / w;
    if (!isfinite(t)) t = 1e30;
    t = fmin(fmax(t, -1e30), 1e30);
    tloc[tid] = t;
  }
  __syncthreads();
  if (tid < HIDDEN) {
    double t = tloc[tid];
    int r = 0;
    for (int k = 0; k < HIDDEN; ++k) {
      double tk = tloc[k];
      r += (tk < t) || (tk == t && k < tid);
    }
    ts[r] = t;
  }
  __syncthreads();
}

// L1: blocks 0..257 = per-interval affine tables; 258..259 = code_out;
// 260..275 = interval-bucket table (256 buckets each).
__global__ void __launch_bounds__(256) k_stage0(
    const float* __restrict__ w1, const float* __restrict__ b1,
    const float* __restrict__ w2, const float* __restrict__ b2,
    const float* __restrict__ emb, const float* __restrict__ decw,
    const float* __restrict__ decb, double* __restrict__ t_sorted,
    double* __restrict__ code_out, unsigned char* __restrict__ ibuck,
    double2* __restrict__ AB) {
  const int blk = blockIdx.x, tid = threadIdx.x;
  if (blk < 258) {
    __shared__ double tloc[HIDDEN], ts[HIDDEN], wj[HIDDEN], bj[HIDDEN];
    sort_thresholds(w1, b1, tloc, ts);
    if (blk == 0 && tid < HIDDEN) t_sorted[tid] = ts[tid];
    const int i = blk >> 1;
    const int c = ((blk & 1) << 8) + tid;
    double xm;
    if (i == 0)           xm = ts[0] - 1.0;
    else if (i == HIDDEN) xm = ts[HIDDEN - 1] + 1.0;
    else                  xm = 0.5 * (ts[i - 1] + ts[i]);
    if (tid < HIDDEN) {
      double w = (double)w1[tid], b = (double)b1[tid];
      bool act = fma(w, xm, b) > 0.0;    // relu sign constant in open interval
      wj[tid] = act ? w : 0.0;
      bj[tid] = act ? b : 0.0;
    }
    __syncthreads();
    const float4* r4 = (const float4*)(w2 + c * HIDDEN);
    double A = 0.0, Bv = 0.0;
    #pragma unroll 8
    for (int q = 0; q < HIDDEN / 4; ++q) {
      const float4 v = r4[q];
      const int j = q * 4;
      A  = fma((double)v.x, wj[j + 0], A);
      A  = fma((double)v.y, wj[j + 1], A);
      A  = fma((double)v.z, wj[j + 2], A);
      A  = fma((double)v.w, wj[j + 3], A);
      Bv = fma((double)v.x, bj[j + 0], Bv);
      Bv = fma((double)v.y, bj[j + 1], Bv);
      Bv = fma((double)v.z, bj[j + 2], Bv);
      Bv = fma((double)v.w, bj[j + 3], Bv);
    }
    AB[(i << 9) + c] = make_double2(A, Bv + (double)b2[c]);
  } else if (blk < 260) {                // code_out: 2 blocks x 256 codes
    __shared__ double sdw[EMBED_DIM];
    sdw[tid] = (double)decw[tid];
    __syncthreads();
    const int c = (blk - 258) * 256 + tid;
    const float4* e4 = (const float4*)(emb + c * EMBED_DIM);
    double s = 0.0;
    #pragma unroll 8
    for (int q = 0; q < EMBED_DIM / 4; ++q) {
      const float4 v = e4[q];
      const int j = q * 4;
      s = fma((double)v.x, sdw[j + 0], s);
      s = fma((double)v.y, sdw[j + 1], s);
      s = fma((double)v.z, sdw[j + 2], s);
      s = fma((double)v.w, sdw[j + 3], s);
    }
    code_out[c] = s + (double)decb[0];
  } else {                               // bucket table: interval of lower edge
    __shared__ double tloc[HIDDEN], ts[HIDDEN];
    sort_thresholds(w1, b1, tloc, ts);
    const int b = (blk - 260) * 256 + tid;
    const unsigned key = (unsigned)b << 20;
    const unsigned u = (key & 0x80000000u) ? (key ^ 0x80000000u) : ~key;
    const float xf = __uint_as_float(u);
    double xb;
    if (xf != xf) xb = (b >= NBUCK / 2) ? 1e300 : -1e300;  // NaN-prefix buckets
    else          xb = (double)xf;
    ibuck[b] = (unsigned char)classify(ts, xb);
    if (b == 0) ibuck[NBUCK] = (unsigned char)HIDDEN;
  }
}

// L2: branchless pairwise envelope membership (proven R2-R8). Dep chain
// split into even/odd accumulator pairs. No atomics (env2 derives counts).
// L as (nL,dL) dL>=0 (dL==0 => -inf); U as (nU,dU) dU<=0 (dU==0 => +inf).
__global__ void __launch_bounds__(256) k_env1(const double2* __restrict__ AB,
                       unsigned char* __restrict__ surv, double* __restrict__ Lx) {
  __shared__ double2 sAB[NUM_CODES];
  __shared__ double sNL[4][64], sDL[4][64], sNU[4][64], sDU[4][64];
  __shared__ int sDead[4][64];
  const int tid = threadIdx.x;
  const int i = blockIdx.x >> 3;
  const int g = blockIdx.x & 7;
  const int w = tid >> 6, lane = tid & 63;
  const int c = (g << 6) + lane;
  const double2* row = AB + (i << 9);
  for (int t = tid; t < NUM_CODES; t += 256) sAB[t] = row[t];
  __syncthreads();
  const double2 my = sAB[c];
  double nL0 = -1.0, dL0 = 0.0, nU0 = -1.0, dU0 = 0.0;
  double nL1 = -1.0, dL1 = 0.0, nU1 = -1.0, dU1 = 0.0;
  int dead = 0;
  const int k0 = w << 7;
  #pragma unroll 4
  for (int kk = 0; kk < 128; kk += 2) {
    {
      const int k = k0 + kk;
      const double2 o = sAB[k];          // wave-uniform -> LDS broadcast
      const double d = my.x - o.x;
      const double n = o.y - my.y;       // x* = n/d
      const bool cL = (d > 0.0) && (n * dL0 > nL0 * d);
      const bool cU = (d < 0.0) && (n * dU0 < nU0 * d);
      nL0 = cL ? n : nL0;  dL0 = cL ? d : dL0;
      nU0 = cU ? n : nU0;  dU0 = cU ? d : dU0;
      dead |= (d == 0.0) && ((n > 0.0) || (n == 0.0 && k < c));
    }
    {
      const int k = k0 + kk + 1;
      const double2 o = sAB[k];
      const double d = my.x - o.x;
      const double n = o.y - my.y;
      const bool cL = (d > 0.0) && (n * dL1 > nL1 * d);
      const bool cU = (d < 0.0) && (n * dU1 < nU1 * d);
      nL1 = cL ? n : nL1;  dL1 = cL ? d : dL1;
      nU1 = cU ? n : nU1;  dU1 = cU ? d : dU1;
      dead |= (d == 0.0) && ((n > 0.0) || (n == 0.0 && k < c));
    }
  }
  if (nL1 * dL0 > nL0 * dL1) { nL0 = nL1; dL0 = dL1; }   // valid incl. sentinels
  if (nU1 * dU0 < nU0 * dU1) { nU0 = nU1; dU0 = dU1; }
  sNL[w][lane] = nL0; sDL[w][lane] = dL0;
  sNU[w][lane] = nU0; sDU[w][lane] = dU0;
  sDead[w][lane] = dead;
  __syncthreads();
  if (tid < 64) {                        // wave 0 merges the 4 k-chunks
    double nL = sNL[0][lane], dL = sDL[0][lane];
    double nU = sNU[0][lane], dU = sDU[0][lane];
    int dd = sDead[0][lane];
    #pragma unroll
    for (int wv = 1; wv < 4; ++wv) {
      double cn = sNL[wv][lane], cd = sDL[wv][lane];
      if (cn * dL > nL * cd) { nL = cn; dL = cd; }
      cn = sNU[wv][lane]; cd = sDU[wv][lane];
      if (cn * dU < nU * cd) { nU = cn; dU = cd; }
      dd |= sDead[wv][lane];
    }
    // L < U with dL>=0, dU<=0: multiply by dL*dU (<0) flips: nL*dU > nU*dL
    const int sv = (!dd) && (dL == 0.0 || dU == 0.0 || (nL * dU > nU * dL));
    const int pair = (i << 9) + c;
    surv[pair] = (unsigned char)sv;
    Lx[pair]   = (dL == 0.0) ? -1e300 : nL / dL;
  }
}

// L3: compact survivors into per-interval slope-sorted segment tables; derive
// env_cnt by popcount (no atomics/zero-init; duplicate writes are benign).
__global__ void __launch_bounds__(256) k_env2(const double2* __restrict__ AB,
                       const unsigned char* __restrict__ surv,
                       const double* __restrict__ Lx,
                       double* __restrict__ env_xs, int* __restrict__ env_idx,
                       int* __restrict__ env_cnt) {
  __shared__ double sA[NUM_CODES];
  const int tid = threadIdx.x;
  const int i = blockIdx.x >> 1;
  const int c = ((blockIdx.x & 1) << 8) + tid;
  const int base = i << 9;
  for (int t = tid; t < NUM_CODES; t += 256)
    sA[t] = surv[base + t] ? AB[base + t].x : 1e300;
  __syncthreads();
  const double myA = sA[c];
  int rank = 0;
  #pragma unroll 8
  for (int k = 0; k < NUM_CODES; ++k) rank += (sA[k] < myA) ? 1 : 0;
  if (surv[base + c]) {
    env_xs[base + rank]  = Lx[base + c];
    env_idx[base + rank] = c;
  }
  if (tid < 64) {                        // wave 0: count survivors
    int cnt = 0;
    #pragma unroll
    for (int m = 0; m < 8; ++m) cnt += (sA[tid + (m << 6)] < 1e300) ? 1 : 0;
    #pragma unroll
    for (int off = 32; off; off >>= 1) cnt += __shfl_xor(cnt, off);
    if (tid == 0) env_cnt[i] = cnt;
  }
}

// L4: per-sample lookup. Interval via bucket table (1 LDS read + ~0-1 refine
// steps) then ~5-step binary search in the interval's segment table (L2).
// 4 samples/thread, float4 I/O -- four dependent chains interleave.
__global__ void __launch_bounds__(256) k_map(const float* __restrict__ x,
                       const double* __restrict__ t_sorted,
                       const int* __restrict__ env_cnt,
                       const double* __restrict__ env_xs,
                       const int* __restrict__ env_idx,
                       const double* __restrict__ code_out,
                       const unsigned char* __restrict__ ibuck,
                       float* __restrict__ out, float* __restrict__ idx_out) {
  __shared__ double ts[HIDDEN];
  __shared__ double sco[NUM_CODES];
  __shared__ int scnt[NUM_INT];
  __shared__ unsigned char sbk[NBUCK + 1];
  const int tid = threadIdx.x;
  if (tid < HIDDEN) ts[tid] = t_sorted[tid];
  if (tid < NUM_INT) scnt[tid] = env_cnt[tid];
  for (int t = tid; t < NUM_CODES; t += 256) sco[t] = code_out[t];
  {  // coalesced uchar staging via uint
    const uint4* src = (const uint4*)ibuck;
    uint4* dst = (uint4*)sbk;
    if (tid < NBUCK / 16) dst[tid] = src[tid];      // 4096 B
    if (tid == 0) sbk[NBUCK] = ibuck[NBUCK];
  }
  __syncthreads();
  const int s = blockIdx.x * 1024 + tid * 4;
  const float4 xv4 = *(const float4*)(x + s);
  const float xs4[4] = {xv4.x, xv4.y, xv4.z, xv4.w};
  float o[4], id[4];
  #pragma unroll
  for (int k = 0; k < 4; ++k) {
    const float xf = xs4[k];
    const double xv = (double)xf;
    const unsigned u = __float_as_uint(xf);
    const unsigned key = (u & 0x80000000u) ? ~u : (u | 0x80000000u);
    const int b = key >> 20;
    int lo = sbk[b], hi = sbk[b + 1];
    while (lo < hi) {                    // refine: first idx with ts[idx] > xv
      const int mid = (lo + hi) >> 1;
      if (ts[mid] > xv) hi = mid; else lo = mid + 1;
    }
    const int i = lo;
    const int base = i << 9;
    int slo = 0, shi = scnt[i] - 1;
    while (slo < shi) {                  // largest j with xs[j] <= xv
      const int mid = (slo + shi + 1) >> 1;
      if (env_xs[base + mid] <= xv) slo = mid; else shi = mid - 1;
    }
    const int ci = env_idx[base + slo];
    o[k]  = (float)sco[ci];
    id[k] = (float)ci;
  }
  *(float4*)(out + s)     = make_float4(o[0], o[1], o[2], o[3]);
  *(float4*)(idx_out + s) = make_float4(id[0], id[1], id[2], id[3]);
}

extern "C" void kernel_launch(void* const* d_in, const int* in_sizes, int n_in,
                              void* d_out, int out_size, void* d_ws, size_t ws_size,
                              hipStream_t stream) {
  const float* x    = (const float*)d_in[0];
  const float* w1   = (const float*)d_in[1];
  const float* b1   = (const float*)d_in[2];
  const float* w2   = (const float*)d_in[3];
  const float* b2   = (const float*)d_in[4];
  const float* emb  = (const float*)d_in[5];
  const float* decw = (const float*)d_in[6];
  const float* decb = (const float*)d_in[7];

  char* ws = (char*)d_ws;
  double*        t_sorted = (double*)        (ws + 0);
  double*        code_out = (double*)        (ws + 2048);
  int*           env_cnt  = (int*)           (ws + 8192);
  unsigned char* ibuck    = (unsigned char*) (ws + 16384);
  unsigned char* surv     = (unsigned char*) (ws + 36864);
  double*        Lx       = (double*)        (ws + 106496);
  double2*       AB       = (double2*)       (ws + 638976);
  double*        env_xs   = (double*)        (ws + 1703936);
  int*           env_idx  = (int*)           (ws + 2236416);

  float* out  = (float*)d_out;
  float* idxo = out + B_SAMPLES;

  k_stage0<<<276,              256, 0, stream>>>(w1, b1, w2, b2, emb, decw, decb,
                                                 t_sorted, code_out, ibuck, AB);
  k_env1  <<<NUM_INT * 8,      256, 0, stream>>>(AB, surv, Lx);
  k_env2  <<<NUM_INT * 2,      256, 0, stream>>>(AB, surv, Lx, env_xs, env_idx, env_cnt);
  k_map   <<<B_SAMPLES / 1024, 256, 0, stream>>>(x, t_sorted, env_cnt, env_xs,
                                                 env_idx, code_out, ibuck, out, idxo);
}